// Round 9
// baseline (123.199 us; speedup 1.0000x reference)
//
#include <hip/hip_runtime.h>

// B=256, C=2048, H*W=128, NUM_CLASSES=10000
// Outputs (fp32, concat): logits[256*10000], logits[256*10000],
//                         neck_feat[256*2048], new_weight[256] (== 1.0 analytically)
// targets are dead.
//
// R9: A/B test vs R8 — identical prep + pipeline skeleton; ONLY change:
// A is staged via plain loads (L2-allocating) + ds_write instead of
// global_load_lds DMA; B stays DMA (true stream). Grid (157,2) so mh pairs
// re-reading wsB are time-separated -> L3 hit.

#define OUT1_OFF (256 * 10000)
#define FEAT_OFF (2 * 256 * 10000)
#define NW_OFF   (2 * 256 * 10000 + 256 * 2048)

typedef __attribute__((ext_vector_type(4))) float f32x4;
typedef __attribute__((ext_vector_type(8))) short bf16x8;
typedef __attribute__((ext_vector_type(4))) unsigned int u32x4;

__device__ inline unsigned pk2bf(float lo, float hi) {
    unsigned a = __float_as_uint(lo), b = __float_as_uint(hi);
    unsigned ra = (a + 0x7FFFu + ((a >> 16) & 1u)) >> 16;
    unsigned rb = (b + 0x7FFFu + ((b >> 16) & 1u)) & 0xFFFF0000u;
    return ra | rb;
}

__device__ inline void gload_lds16(const void* g, void* l) {
    __builtin_amdgcn_global_load_lds(
        (const __attribute__((address_space(1))) void*)g,
        (__attribute__((address_space(3))) void*)l, 16, 0, 0);
}

// ---------------------------------------------------------------------------
// Kernel 1 (prep): BYTE-IDENTICAL to R8. Blocks [0,32768) = pool (R2
// structure); blocks [32768,33393) = wconv (W fp32 -> bf16 B-fragment-major).
//   A-chunk(m,k)=((m>>4)*256+(k>>3))*16+(m&15), word (k&7)>>1  (wsA)
//   B-chunk(n,k)=((n>>4)*256+(k>>3))*16+(n&15)                 (wsB)
// ---------------------------------------------------------------------------
__global__ __launch_bounds__(256) void prep_kernel(
    const float* __restrict__ f, const float* __restrict__ W,
    float* __restrict__ out, unsigned int* __restrict__ wsA32,
    u32x4* __restrict__ wsB) {
    int bid = blockIdx.x;
    int tid = threadIdx.x;
    if (bid < 32768) {
        int g = tid >> 5;
        int l = tid & 31;
        int r0 = bid * 16 + g * 2;  // rows r0, r0+1 (r0 even)
        const f32x4* s0 = (const f32x4*)(f + (size_t)r0 * 128);
        f32x4 v0 = s0[l];
        f32x4 v1 = s0[l + 32];
        float a = v0[0] + v0[1] + v0[2] + v0[3];
        float b = v1[0] + v1[1] + v1[2] + v1[3];
#pragma unroll
        for (int off = 16; off >= 1; off >>= 1) {
            a += __shfl_xor(a, off);
            b += __shfl_xor(b, off);
        }
        if (l == 0) {
            float m0 = a * (1.0f / 128.0f), m1 = b * (1.0f / 128.0f);
            float2 fv; fv.x = m0; fv.y = m1;
            *(float2*)&out[FEAT_OFF + r0] = fv;
            int bb = r0 >> 11, c = r0 & 2047;
            int chunk = ((bb >> 4) * 256 + (c >> 3)) * 16 + (bb & 15);
            wsA32[chunk * 4 + ((c & 7) >> 1)] = pk2bf(m0, m1);
        }
        if (bid == 0) out[NW_OFF + tid] = 1.0f;
    } else {
        int nb = bid - 32768;  // 0..624
        int n0 = nb * 16;
        int r = tid & 15, kq = tid >> 4;  // kq 0..15
        const f32x4* src = (const f32x4*)(W + (size_t)(n0 + r) * 2048) + kq * 2;
        u32x4* dst = wsB + ((size_t)(n0 >> 4) * 256 + kq) * 16 + r;
#pragma unroll
        for (int kc = 0; kc < 16; ++kc) {
            f32x4 a = src[kc * 32], b = src[kc * 32 + 1];
            u32x4 p;
            p.x = pk2bf(a[0], a[1]);
            p.y = pk2bf(a[2], a[3]);
            p.z = pk2bf(b[0], b[1]);
            p.w = pk2bf(b[2], b[3]);
            dst[kc * 256] = p;
        }
    }
}

// ---------------------------------------------------------------------------
// Kernel 2 (GEMM): BM=128, BN=64, BK=64; grid (157, 2); 512 thr = 8 waves
// (4m x 2n, wave tile 32x32). Tri-buffered LDS 72 KB -> 2 blocks/CU.
// A: plain global_load_dwordx4 -> regs -> ds_write_b128 (L2-allocating).
// B: global_load_lds DMA (pure stream). Depth-2; prologue vmcnt(1),
// steady-state vmcnt(3); one s_barrier per kt.
// ---------------------------------------------------------------------------
__global__ __launch_bounds__(512) void gemm_kernel(
    const u32x4* __restrict__ A16, const u32x4* __restrict__ B16,
    float* __restrict__ out) {
    __shared__ u32x4 As[3][1024];  // 16 KB per buf
    __shared__ u32x4 Bs[3][512];   // 8 KB per buf -> 72 KB total

    int tid = threadIdx.x;
    int n0 = blockIdx.x * 64;  // 0..156 (last tile cols 9984..10047 predicated)
    int mh = blockIdx.y;       // 0..1
    int wid = tid >> 6, lane = tid & 63;
    int wm = wid >> 1, wn = wid & 1;
    int r = lane & 15, kqu = lane >> 4;

    // A chunks: ci = tid + i*512 -> mf'=ci>>7 (0..7), kg=(ci>>4)&7, rr=ci&15
    const u32x4* ga[2];
#pragma unroll
    for (int i = 0; i < 2; ++i) {
        int ci = tid + i * 512;
        ga[i] = A16 + (((mh * 8 + (ci >> 7)) * 256 + ((ci >> 4) & 7)) * 16 + (ci & 15));
    }
    // B chunk: tid -> nf'=tid>>7, kg=(tid>>4)&7, rr=tid&15; 1KB runs per wave
    const u32x4* gb = B16 + ((size_t)(n0 >> 4) * 4096 + (tid >> 7) * 4096 + (tid & 127));

    f32x4 acc[2][2];
#pragma unroll
    for (int i = 0; i < 2; ++i)
#pragma unroll
        for (int j = 0; j < 2; ++j) acc[i][j] = (f32x4){0.f, 0.f, 0.f, 0.f};

    u32x4 RX0, RX1, RY0, RY1;  // A reg-staging, X=even kt, Y=odd kt

#define ALOAD(kt, R0_, R1_)      \
    {                            \
        R0_ = ga[0][(kt) * 128]; \
        R1_ = ga[1][(kt) * 128]; \
    }
#define AWRITE(buf, R0_, R1_)    \
    {                            \
        As[buf][tid] = R0_;      \
        As[buf][tid + 512] = R1_;\
    }
#define BDMA(kt, buf) gload_lds16(gb + (kt) * 128, &Bs[buf][tid]);

    // ---- prologue: tiles 0,1 in flight ----
    ALOAD(0, RX0, RX1);
    BDMA(0, 0);
    ALOAD(1, RY0, RY1);
    BDMA(1, 1);
    asm volatile("s_waitcnt vmcnt(1)" ::: "memory");  // tile0 fully landed (+A1 mostly)
    __builtin_amdgcn_sched_barrier(0);
    AWRITE(0, RX0, RX1);
    asm volatile("s_waitcnt lgkmcnt(0)" ::: "memory");
    __builtin_amdgcn_sched_barrier(0);
    __builtin_amdgcn_s_barrier();
    __builtin_amdgcn_sched_barrier(0);

    for (int kt = 0; kt < 32; ++kt) {
        int cur = kt % 3;
        // issue tile kt+2: A -> regs (plain loads), B -> LDS DMA
        if (kt <= 29) {
            int nx2 = (kt + 2) % 3;
            if (kt & 1) { ALOAD(kt + 2, RY0, RY1); }
            else        { ALOAD(kt + 2, RX0, RX1); }
            BDMA(kt + 2, nx2);
        }
        // compute tile kt
#pragma unroll
        for (int ks = 0; ks < 2; ++ks) {
            int kcl = ks * 4 + kqu;
            bf16x8 av[2], bv[2];
#pragma unroll
            for (int i = 0; i < 2; ++i)
                av[i] = *(const bf16x8*)&As[cur][(wm * 2 + i) * 128 + kcl * 16 + r];
#pragma unroll
            for (int j = 0; j < 2; ++j)
                bv[j] = *(const bf16x8*)&Bs[cur][(wn * 2 + j) * 128 + kcl * 16 + r];
#pragma unroll
            for (int i = 0; i < 2; ++i)
#pragma unroll
                for (int j = 0; j < 2; ++j)
                    acc[i][j] = __builtin_amdgcn_mfma_f32_16x16x32_bf16(
                        av[i], bv[j], acc[i][j], 0, 0, 0);
        }
        // finish tile kt+1: its 3 vm ops are the oldest (kt+2's 3 newest stay out)
        if (kt <= 29)      { asm volatile("s_waitcnt vmcnt(3)" ::: "memory"); }
        else if (kt == 30) { asm volatile("s_waitcnt vmcnt(0)" ::: "memory"); }
        __builtin_amdgcn_sched_barrier(0);
        if (kt <= 30) {
            int nx1 = (kt + 1) % 3;
            if (kt & 1) { AWRITE(nx1, RX0, RX1); }
            else        { AWRITE(nx1, RY0, RY1); }
            asm volatile("s_waitcnt lgkmcnt(0)" ::: "memory");
            __builtin_amdgcn_sched_barrier(0);
            __builtin_amdgcn_s_barrier();
        }
        __builtin_amdgcn_sched_barrier(0);
    }

    // ---- epilogue: C and C*SCALE (SCALE=1) ----
#pragma unroll
    for (int i = 0; i < 2; ++i)
#pragma unroll
        for (int j = 0; j < 2; ++j) {
            int n = n0 + (wn * 2 + j) * 16 + r;
            if (n < 10000) {
                int mbase = mh * 128 + (wm * 2 + i) * 16 + kqu * 4;
#pragma unroll
                for (int q = 0; q < 4; ++q) {
                    float v = acc[i][j][q];
                    size_t off = (size_t)(mbase + q) * 10000 + n;
                    out[off] = v;
                    out[OUT1_OFF + off] = v;
                }
            }
        }
#undef ALOAD
#undef AWRITE
#undef BDMA
}

extern "C" void kernel_launch(void* const* d_in, const int* in_sizes, int n_in,
                              void* d_out, int out_size, void* d_ws, size_t ws_size,
                              hipStream_t stream) {
    const float* feats = (const float*)d_in[0];
    // d_in[1] = targets (int32) — dead (new_weight == ones analytically)
    const float* weight = (const float*)d_in[2];
    float* out = (float*)d_out;
    unsigned int* wsA = (unsigned int*)d_ws;          // 1 MB
    u32x4* wsB = (u32x4*)((char*)d_ws + (2u << 20));  // ~41 MB

    prep_kernel<<<33393, 256, 0, stream>>>(feats, weight, out, wsA, wsB);
    gemm_kernel<<<dim3(157, 2), 512, 0, stream>>>((const u32x4*)wsA, wsB, out);
}